// Round 5
// baseline (985.490 us; speedup 1.0000x reference)
//
#include <hip/hip_runtime.h>

#define N_ROWS   131072
#define D_IN     256
#define D_MID    128
#define N_SUBS   64

// ws layout: rowsum[N_ROWS] floats | gbins[128] (64 group sums + 64 counts)

// K1: one wave per row (32768 blocks x 4 waves). Lane l loads float4 at col
// 4l (fully coalesced 1 KiB/wave), 6-step shfl_xor tree reduce, lane 0 stores
// rowsum and issues 2 fire-and-forget global atomics into the 128-entry group
// bins (262K atomics over 128 L2 addresses, overlapped with the stream).
// No loop -> no loop-carried serialization; block turnover hides latency.
__global__ __launch_bounds__(256) void k1_rowsum_bins(const float* __restrict__ x,
                                                      const int* __restrict__ sub,
                                                      float* __restrict__ rowsum,
                                                      float* __restrict__ gbins) {
    int row  = blockIdx.x * 4 + (threadIdx.x >> 6);
    int lane = threadIdx.x & 63;
    float4 v = ((const float4*)(x + (size_t)row * D_IN))[lane];
    float s = (v.x + v.y) + (v.z + v.w);
    #pragma unroll
    for (int m = 32; m >= 1; m >>= 1) s += __shfl_xor(s, m, 64);
    if (lane == 0) {
        rowsum[row] = s;
        int g = sub[row];
        atomicAdd(&gbins[g], s);              // group sum
        atomicAdd(&gbins[N_SUBS + g], 1.0f);  // group count
    }
}

// K2: one wave per row, tg computed inline per wave from wave-uniform
// broadcast loads (rowsum[row], sub[row], gbins[g], gbins[64+g], rowsum[0],
// Gamma, Lambda — all single-transaction L2 hits), then one 1 KiB coalesced
// float4 broadcast store. No prologue, no __syncthreads, nothing between
// block launch and the store except ~10 scalar ops.
__global__ __launch_bounds__(256) void k2_out(const float* __restrict__ rowsum,
                                              const int* __restrict__ sub,
                                              const float* __restrict__ gbins,
                                              const float* __restrict__ Gamma,
                                              const float* __restrict__ Lambda,
                                              float* __restrict__ out) {
    int row  = blockIdx.x * 4 + (threadIdx.x >> 6);
    int lane = threadIdx.x & 63;
    float rs  = rowsum[row];                  // wave-uniform broadcast load
    int   g   = sub[row];
    float sum = gbins[g];
    float cnt = gbins[N_SUBS + g];
    // empty-group fallback: mean over x[0] -> meansum == rowsum[0]
    float meansum = (cnt > 0.0f) ? (sum / cnt) : rowsum[0];
    float s = Gamma[0] * meansum;
    s = s > 0.0f ? s : 0.0f;                  // relu
    float o = Lambda[0] * (rs + (float)D_MID * s);
    o = o > 0.0f ? o : 0.0f;                  // relu
    ((float4*)(out + (size_t)row * D_IN))[lane] = make_float4(o, o, o, o);
}

extern "C" void kernel_launch(void* const* d_in, const int* in_sizes, int n_in,
                              void* d_out, int out_size, void* d_ws, size_t ws_size,
                              hipStream_t stream) {
    const float* x      = (const float*)d_in[0];
    const int*   sub    = (const int*)d_in[1];
    const float* Gamma  = (const float*)d_in[2];
    const float* Lambda = (const float*)d_in[3];
    float* out = (float*)d_out;

    float* rowsum = (float*)d_ws;             // N_ROWS floats
    float* gbins  = rowsum + N_ROWS;          // 128 floats (sums | counts)

    hipMemsetAsync(gbins, 0, 2 * N_SUBS * sizeof(float), stream);  // graph-capturable
    k1_rowsum_bins<<<N_ROWS / 4, 256, 0, stream>>>(x, sub, rowsum, gbins);
    k2_out<<<N_ROWS / 4, 256, 0, stream>>>(rowsum, sub, gbins, Gamma, Lambda, out);
}

// Round 6
// 242.178 us; speedup vs baseline: 4.0693x; 4.0693x over previous
//
#include <hip/hip_runtime.h>

#define N_ROWS   131072
#define D_IN     256
#define D_MID    128
#define N_SUBS   64

// ws layout: rowsum[N_ROWS] floats | gbins[128] (64 group sums | 64 counts)

// K1: one wave per row (32768 blocks x 4 waves). Lane l loads float4 at col
// 4l (coalesced 1 KiB/wave), 6-step shfl_xor reduce, lane 0 stores rowsum.
// NO atomics here (round-5 lesson: 262K contended global atomics = 791 us).
// Block 0 zeroes the 128 group bins (consumed only by k2 -> no race).
__global__ __launch_bounds__(256) void k1_rowsum(const float* __restrict__ x,
                                                 float* __restrict__ rowsum,
                                                 float* __restrict__ bins) {
    if (blockIdx.x == 0 && threadIdx.x < 2 * N_SUBS) bins[threadIdx.x] = 0.0f;
    int row  = blockIdx.x * 4 + (threadIdx.x >> 6);
    int lane = threadIdx.x & 63;
    float4 v = ((const float4*)(x + (size_t)row * D_IN))[lane];
    float s = (v.x + v.y) + (v.z + v.w);
    #pragma unroll
    for (int m = 32; m >= 1; m >>= 1) s += __shfl_xor(s, m, 64);
    if (lane == 0) rowsum[row] = s;
}

// K2: hierarchical group binning. 128 blocks x 256 threads; each thread owns
// exactly 4 consecutive rows via ONE float4 rowsum load + ONE int4 sub load
// (no loop), 8 LDS atomics, then 128 global atomics per block (16K total,
// 2048-to-1 aggregation -> no contention wall).
__global__ __launch_bounds__(256) void k2_group(const float* __restrict__ rowsum,
                                                const int* __restrict__ sub,
                                                float* __restrict__ gbins) {
    __shared__ float ls[2 * N_SUBS];
    int tid = threadIdx.x;
    if (tid < 2 * N_SUBS) ls[tid] = 0.0f;
    __syncthreads();

    int base = (blockIdx.x * 256 + tid) * 4;          // 4 rows per thread
    float4 rs = *(const float4*)(rowsum + base);
    int4   sg = *(const int4*)(sub + base);
    atomicAdd(&ls[sg.x], rs.x);  atomicAdd(&ls[N_SUBS + sg.x], 1.0f);
    atomicAdd(&ls[sg.y], rs.y);  atomicAdd(&ls[N_SUBS + sg.y], 1.0f);
    atomicAdd(&ls[sg.z], rs.z);  atomicAdd(&ls[N_SUBS + sg.z], 1.0f);
    atomicAdd(&ls[sg.w], rs.w);  atomicAdd(&ls[N_SUBS + sg.w], 1.0f);

    __syncthreads();
    if (tid < 2 * N_SUBS) atomicAdd(&gbins[tid], ls[tid]);
}

// K3: one wave per row; all scalar inputs are wave-uniform L2-hot broadcast
// loads; one 1 KiB coalesced float4 broadcast store per row.
__global__ __launch_bounds__(256) void k3_out(const float* __restrict__ rowsum,
                                              const int* __restrict__ sub,
                                              const float* __restrict__ gbins,
                                              const float* __restrict__ Gamma,
                                              const float* __restrict__ Lambda,
                                              float* __restrict__ out) {
    int row  = blockIdx.x * 4 + (threadIdx.x >> 6);
    int lane = threadIdx.x & 63;
    float rs  = rowsum[row];
    int   g   = sub[row];
    float sum = gbins[g];
    float cnt = gbins[N_SUBS + g];
    // empty-group fallback: mean over x[0] -> meansum == rowsum[0]
    float meansum = (cnt > 0.0f) ? (sum / cnt) : rowsum[0];
    float s = Gamma[0] * meansum;
    s = s > 0.0f ? s : 0.0f;                          // relu
    float o = Lambda[0] * (rs + (float)D_MID * s);
    o = o > 0.0f ? o : 0.0f;                          // relu
    ((float4*)(out + (size_t)row * D_IN))[lane] = make_float4(o, o, o, o);
}

extern "C" void kernel_launch(void* const* d_in, const int* in_sizes, int n_in,
                              void* d_out, int out_size, void* d_ws, size_t ws_size,
                              hipStream_t stream) {
    const float* x      = (const float*)d_in[0];
    const int*   sub    = (const int*)d_in[1];
    const float* Gamma  = (const float*)d_in[2];
    const float* Lambda = (const float*)d_in[3];
    float* out = (float*)d_out;

    float* rowsum = (float*)d_ws;                     // N_ROWS floats
    float* gbins  = rowsum + N_ROWS;                  // 128 floats (sums | counts)

    k1_rowsum<<<N_ROWS / 4, 256, 0, stream>>>(x, rowsum, gbins);
    k2_group<<<128, 256, 0, stream>>>(rowsum, sub, gbins);
    k3_out<<<N_ROWS / 4, 256, 0, stream>>>(rowsum, sub, gbins, Gamma, Lambda, out);
}

// Round 7
// 240.669 us; speedup vs baseline: 4.0948x; 1.0063x over previous
//
#include <hip/hip_runtime.h>

#define N_ROWS   131072
#define D_IN     256
#define D_MID    128
#define N_SUBS   64

// ws layout: rowsum[N_ROWS] floats | gbins[128] (64 group sums | 64 counts)

// K1: 2 rows per wave, straight-line (no loop, no side effects between the
// loads). Two back-to-back float4 loads (2 KiB in flight per wave), two
// independent shfl_xor chains that interleave, then lane 0 stores both sums
// as one float2. Block 0 zeroes the group bins (consumed only by k2).
__global__ __launch_bounds__(256) void k1_rowsum(const float* __restrict__ x,
                                                 float* __restrict__ rowsum,
                                                 float* __restrict__ bins) {
    if (blockIdx.x == 0 && threadIdx.x < 2 * N_SUBS) bins[threadIdx.x] = 0.0f;
    int wave = blockIdx.x * 4 + (threadIdx.x >> 6);
    int lane = threadIdx.x & 63;
    int row0 = wave * 2;
    const float4* p = (const float4*)(x + (size_t)row0 * D_IN);
    float4 a = p[lane];            // row0: 1 KiB coalesced
    float4 b = p[64 + lane];       // row1: next 1 KiB, issued before any ALU dep
    float s0 = (a.x + a.y) + (a.z + a.w);
    float s1 = (b.x + b.y) + (b.z + b.w);
    #pragma unroll
    for (int m = 32; m >= 1; m >>= 1) {
        s0 += __shfl_xor(s0, m, 64);   // two independent chains -> interleaved
        s1 += __shfl_xor(s1, m, 64);
    }
    if (lane == 0) *(float2*)(rowsum + row0) = make_float2(s0, s1);
}

// K2: hierarchical group binning (proven shape). 128 blocks x 256 threads;
// each thread owns 4 rows via one float4 + one int4 load, 8 LDS atomics,
// then 128 global atomics per block (16K total -> no contention wall).
__global__ __launch_bounds__(256) void k2_group(const float* __restrict__ rowsum,
                                                const int* __restrict__ sub,
                                                float* __restrict__ gbins) {
    __shared__ float ls[2 * N_SUBS];
    int tid = threadIdx.x;
    if (tid < 2 * N_SUBS) ls[tid] = 0.0f;
    __syncthreads();

    int base = (blockIdx.x * 256 + tid) * 4;
    float4 rs = *(const float4*)(rowsum + base);
    int4   sg = *(const int4*)(sub + base);
    atomicAdd(&ls[sg.x], rs.x);  atomicAdd(&ls[N_SUBS + sg.x], 1.0f);
    atomicAdd(&ls[sg.y], rs.y);  atomicAdd(&ls[N_SUBS + sg.y], 1.0f);
    atomicAdd(&ls[sg.z], rs.z);  atomicAdd(&ls[N_SUBS + sg.z], 1.0f);
    atomicAdd(&ls[sg.w], rs.w);  atomicAdd(&ls[N_SUBS + sg.w], 1.0f);

    __syncthreads();
    if (tid < 2 * N_SUBS) atomicAdd(&gbins[tid], ls[tid]);
}

// K3: 4 rows per wave, straight-line. rowsum/sub for the 4 aligned rows are
// single lane-uniform float4/int4 broadcast loads; per-group terms are L2-hot
// scalar loads; then 4 independent fire-and-forget 1 KiB float4 stores.
// No LDS, no syncthreads, no divergence.
__global__ __launch_bounds__(256) void k3_out(const float* __restrict__ rowsum,
                                              const int* __restrict__ sub,
                                              const float* __restrict__ gbins,
                                              const float* __restrict__ Gamma,
                                              const float* __restrict__ Lambda,
                                              float* __restrict__ out) {
    int wave = blockIdx.x * 4 + (threadIdx.x >> 6);
    int lane = threadIdx.x & 63;
    int row0 = wave * 4;
    float4 rs = *(const float4*)(rowsum + row0);   // lane-uniform 16 B
    int4   sg = *(const int4*)(sub + row0);        // lane-uniform 16 B
    float gam = Gamma[0], lam = Lambda[0];
    float rs0 = rowsum[0];                          // empty-group fallback term

    float o[4];
    int   g[4]  = {sg.x, sg.y, sg.z, sg.w};
    float r[4]  = {rs.x, rs.y, rs.z, rs.w};
    #pragma unroll
    for (int j = 0; j < 4; ++j) {
        float sum = gbins[g[j]];
        float cnt = gbins[N_SUBS + g[j]];
        float meansum = (cnt > 0.0f) ? (sum / cnt) : rs0;  // mean over x[0] fallback
        float s = gam * meansum;
        s = s > 0.0f ? s : 0.0f;                           // relu
        float t = lam * (r[j] + (float)D_MID * s);
        o[j] = t > 0.0f ? t : 0.0f;                        // relu
    }
    float4* dst = (float4*)(out + (size_t)row0 * D_IN);
    #pragma unroll
    for (int j = 0; j < 4; ++j)
        dst[(size_t)j * 64 + lane] = make_float4(o[j], o[j], o[j], o[j]);
}

extern "C" void kernel_launch(void* const* d_in, const int* in_sizes, int n_in,
                              void* d_out, int out_size, void* d_ws, size_t ws_size,
                              hipStream_t stream) {
    const float* x      = (const float*)d_in[0];
    const int*   sub    = (const int*)d_in[1];
    const float* Gamma  = (const float*)d_in[2];
    const float* Lambda = (const float*)d_in[3];
    float* out = (float*)d_out;

    float* rowsum = (float*)d_ws;                 // N_ROWS floats
    float* gbins  = rowsum + N_ROWS;              // 128 floats (sums | counts)

    k1_rowsum<<<N_ROWS / 8, 256, 0, stream>>>(x, rowsum, gbins);
    k2_group<<<128, 256, 0, stream>>>(rowsum, sub, gbins);
    k3_out<<<N_ROWS / 16, 256, 0, stream>>>(rowsum, sub, gbins, Gamma, Lambda, out);
}